// Round 1
// baseline (1634.272 us; speedup 1.0000x reference)
//
#include <hip/hip_runtime.h>
#include <cstdint>
#include <cstddef>

#define BN_EPS 1e-5f

// ---------------- graph preprocessing ----------------

__device__ __forceinline__ int edge_at(const void* e, long long i, int m64) {
  return m64 ? (int)((const long long*)e)[i] : ((const int*)e)[i];
}

// Detect int64 vs int32 edge_index: values are 0..99999 (non-negative, <2^31),
// so for int64 data every odd 32-bit word is 0. For int32 data odd words are
// random row indices -> ~impossible to all be zero.
__global__ void detect_kernel(const int* __restrict__ e, int* __restrict__ mode) {
  int nz = 0;
  for (int i = 1; i < 512; i += 2) nz |= e[i];
  mode[0] = (nz == 0) ? 1 : 0;
}

__global__ void deg_kernel(const void* __restrict__ edges, const int* __restrict__ mode,
                           int* __restrict__ deg, int E) {
  int m = mode[0];
  long long i = (long long)blockIdx.x * blockDim.x + threadIdx.x;
  long long stride = (long long)gridDim.x * blockDim.x;
  for (; i < E; i += stride) {
    atomicAdd(&deg[edge_at(edges, (long long)E + i, m)], 1);
  }
}

__global__ void dinv_kernel(const int* __restrict__ deg, float* __restrict__ dinv, int n) {
  int i = blockIdx.x * blockDim.x + threadIdx.x;
  if (i < n) dinv[i] = deg[i] > 0 ? rsqrtf((float)deg[i]) : 0.f;
}

// Single-block scan of degrees -> CSR offsets (+ cursor copy for the fill pass)
__global__ void scan_kernel(const int* __restrict__ deg, int* __restrict__ offsets,
                            int* __restrict__ cursor, int n) {
  __shared__ int sums[1024];
  int t = threadIdx.x;
  int chunk = (n + 1023) >> 10;
  long long lo = (long long)t * chunk;
  long long hi = lo + chunk;
  if (hi > n) hi = n;
  if (lo > n) lo = n;
  int s = 0;
  for (long long i = lo; i < hi; i++) s += deg[i];
  sums[t] = s;
  __syncthreads();
  for (int off = 1; off < 1024; off <<= 1) {
    int v = (t >= off) ? sums[t - off] : 0;
    __syncthreads();
    sums[t] += v;
    __syncthreads();
  }
  int run = sums[t] - s;  // exclusive prefix of this chunk
  for (long long i = lo; i < hi; i++) {
    offsets[i] = run;
    cursor[i] = run;
    run += deg[i];
  }
  if (hi == n) offsets[n] = run;
}

__global__ void fill_kernel(const void* __restrict__ edges, const int* __restrict__ mode,
                            int* __restrict__ cursor, int* __restrict__ csr_row, int E) {
  int m = mode[0];
  long long i = (long long)blockIdx.x * blockDim.x + threadIdx.x;
  long long stride = (long long)gridDim.x * blockDim.x;
  for (; i < E; i += stride) {
    int c = edge_at(edges, (long long)E + i, m);
    int r = edge_at(edges, i, m);
    int p = atomicAdd(&cursor[c], 1);
    csr_row[p] = r;
  }
}

// ---------------- per-layer kernels ----------------

// x[i][:] = dinv[i] * ( affine(in[i][:]) @ W )   (affine = fused BN of prev layer)
// Tile: 64 rows x 128 cols per 256-thread block, K tiled by 32.
__global__ __launch_bounds__(256) void gemm_kernel(
    const float* __restrict__ in, const float* __restrict__ W,
    const float* __restrict__ scale, const float* __restrict__ shift, int use_affine,
    const float* __restrict__ dinv, float* __restrict__ x, int n) {
  __shared__ float A[64][33];    // +1 pad: avoid same-bank across rows
  __shared__ float Bs[32][128];
  int tid = threadIdx.x;
  int row0 = blockIdx.x * 64;
  int tc = tid & 15;   // col group: cols tc*8 .. tc*8+7
  int tr = tid >> 4;   // row group: rows tr*4 .. tr*4+3
  float acc[4][8] = {};

  for (int kt = 0; kt < 128; kt += 32) {
    // load A tile 64x32 (2 float4 per thread), with optional BN affine on columns
    {
      int r = tid >> 2;
      int c = (tid & 3) * 8;
      int grow = row0 + r;
      if (grow < n) {
        const float* src = in + (size_t)grow * 128 + kt + c;
        float4 v0 = *(const float4*)(src);
        float4 v1 = *(const float4*)(src + 4);
        float vv[8] = {v0.x, v0.y, v0.z, v0.w, v1.x, v1.y, v1.z, v1.w};
        if (use_affine) {
#pragma unroll
          for (int j = 0; j < 8; j++) vv[j] = vv[j] * scale[kt + c + j] + shift[kt + c + j];
        }
#pragma unroll
        for (int j = 0; j < 8; j++) A[r][c + j] = vv[j];
      } else {
#pragma unroll
        for (int j = 0; j < 8; j++) A[r][c + j] = 0.f;
      }
    }
    // load W tile 32x128 (4 float4 per thread)
    {
      int kr = tid >> 3;
      int c = (tid & 7) * 16;
      const float* src = W + (size_t)(kt + kr) * 128 + c;
      float4* dst = (float4*)&Bs[kr][c];
      dst[0] = ((const float4*)src)[0];
      dst[1] = ((const float4*)src)[1];
      dst[2] = ((const float4*)src)[2];
      dst[3] = ((const float4*)src)[3];
    }
    __syncthreads();
#pragma unroll
    for (int k = 0; k < 32; k++) {
      float av[4];
#pragma unroll
      for (int i = 0; i < 4; i++) av[i] = A[tr * 4 + i][k];
      float4 b0 = *(const float4*)&Bs[k][tc * 8];
      float4 b1 = *(const float4*)&Bs[k][tc * 8 + 4];
      float bv[8] = {b0.x, b0.y, b0.z, b0.w, b1.x, b1.y, b1.z, b1.w};
#pragma unroll
      for (int i = 0; i < 4; i++)
#pragma unroll
        for (int j = 0; j < 8; j++) acc[i][j] += av[i] * bv[j];
    }
    __syncthreads();
  }

#pragma unroll
  for (int i = 0; i < 4; i++) {
    int grow = row0 + tr * 4 + i;
    if (grow < n) {
      float dv = dinv[grow];
      float4 o0 = make_float4(acc[i][0] * dv, acc[i][1] * dv, acc[i][2] * dv, acc[i][3] * dv);
      float4 o1 = make_float4(acc[i][4] * dv, acc[i][5] * dv, acc[i][6] * dv, acc[i][7] * dv);
      *(float4*)(x + (size_t)grow * 128 + tc * 8) = o0;
      *(float4*)(x + (size_t)grow * 128 + tc * 8 + 4) = o1;
    }
  }
}

// z[c][:] = dinv[c] * sum over incoming edges of x[row][:]
__global__ __launch_bounds__(256) void agg_kernel(
    const float* __restrict__ x, const int* __restrict__ csr_row,
    const int* __restrict__ offsets, const float* __restrict__ dinv,
    float* __restrict__ z, int n) {
  int node = blockIdx.x * 2 + (threadIdx.x >> 7);
  int d = threadIdx.x & 127;
  if (node >= n) return;
  int lo = offsets[node], hi = offsets[node + 1];
  float acc = 0.f;
  for (int e = lo; e < hi; e++) {
    int r = csr_row[e];
    acc += x[(size_t)r * 128 + d];
  }
  z[(size_t)node * 128 + d] = acc * dinv[node];
}

__global__ __launch_bounds__(128) void stats_kernel(
    const float* __restrict__ z, float* __restrict__ colsum,
    float* __restrict__ colsumsq, int n) {
  int d = threadIdx.x;
  float s = 0.f, s2 = 0.f;
  for (int r = blockIdx.x; r < n; r += gridDim.x) {
    float v = z[(size_t)r * 128 + d];
    s += v;
    s2 += v * v;
  }
  atomicAdd(&colsum[d], s);
  atomicAdd(&colsumsq[d], s2);
}

__global__ void finalize_kernel(const float* __restrict__ colsum,
                                const float* __restrict__ colsumsq,
                                const float* __restrict__ gamma,
                                const float* __restrict__ beta,
                                float* __restrict__ scale, float* __restrict__ shift,
                                float invN) {
  int d = threadIdx.x;
  float mu = colsum[d] * invN;
  float var = colsumsq[d] * invN - mu * mu;
  var = fmaxf(var, 0.f);
  float sc = gamma[d] * rsqrtf(var + BN_EPS);
  scale[d] = sc;
  shift[d] = beta[d] - mu * sc;
}

__global__ __launch_bounds__(256) void norm_kernel(
    const float* __restrict__ z, const float* __restrict__ scale,
    const float* __restrict__ shift, float* __restrict__ out, int total4) {
  int idx = blockIdx.x * blockDim.x + threadIdx.x;
  int stride = gridDim.x * blockDim.x;
  for (int i = idx; i < total4; i += stride) {
    float4 v = ((const float4*)z)[i];
    int d0 = (i & 31) * 4;
    v.x = v.x * scale[d0] + shift[d0];
    v.y = v.y * scale[d0 + 1] + shift[d0 + 1];
    v.z = v.z * scale[d0 + 2] + shift[d0 + 2];
    v.w = v.w * scale[d0 + 3] + shift[d0 + 3];
    ((float4*)out)[i] = v;
  }
}

// ---------------- launcher ----------------

extern "C" void kernel_launch(void* const* d_in, const int* in_sizes, int n_in,
                              void* d_out, int out_size, void* d_ws, size_t ws_size,
                              hipStream_t stream) {
  const float* feats = (const float*)d_in[0];
  const void* edges = d_in[1];
  const float* W = (const float*)d_in[2];
  // d_in[3] = b : cancels under BN (mean-subtracted), skip
  const float* gamma = (const float*)d_in[4];
  const float* beta = (const float*)d_in[5];

  const int n = in_sizes[0] / 128;
  const int E = in_sizes[1] / 2;

  char* ws = (char*)d_ws;
  size_t off = 0;
  float* x = (float*)(ws + off); off += (size_t)n * 128 * 4;
  int* deg = (int*)(ws + off); off += (size_t)n * 4;
  float* dinv = (float*)(ws + off); off += (size_t)n * 4;
  int* offsets = (int*)(ws + off); off += (size_t)(n + 1) * 4; off = (off + 255) & ~(size_t)255;
  int* cursor = (int*)(ws + off); off += (size_t)n * 4; off = (off + 255) & ~(size_t)255;
  int* csr_row = (int*)(ws + off); off += (size_t)E * 4; off = (off + 255) & ~(size_t)255;
  float* colsum = (float*)(ws + off); off += 128 * 4;
  float* colsumsq = (float*)(ws + off); off += 128 * 4;
  float* scale = (float*)(ws + off); off += 128 * 4;
  float* shift = (float*)(ws + off); off += 128 * 4;
  int* mode = (int*)(ws + off); off += 4;

  // preprocessing (graph is layer-invariant)
  hipMemsetAsync(deg, 0, (size_t)n * 4, stream);
  detect_kernel<<<1, 1, 0, stream>>>((const int*)edges, mode);
  deg_kernel<<<2048, 256, 0, stream>>>(edges, mode, deg, E);
  dinv_kernel<<<(n + 255) / 256, 256, 0, stream>>>(deg, dinv, n);
  scan_kernel<<<1, 1024, 0, stream>>>(deg, offsets, cursor, n);
  fill_kernel<<<2048, 256, 0, stream>>>(edges, mode, cursor, csr_row, E);

  float* z = (float*)d_out;  // z buffer lives in d_out; fully rewritten every layer
  for (int l = 0; l < 3; l++) {
    const float* in = (l == 0) ? feats : z;
    gemm_kernel<<<(n + 63) / 64, 256, 0, stream>>>(
        in, W + (size_t)l * 128 * 128, scale, shift, l > 0 ? 1 : 0, dinv, x, n);
    hipMemsetAsync(colsum, 0, 2 * 128 * 4, stream);  // colsum+colsumsq contiguous
    agg_kernel<<<(n + 1) / 2, 256, 0, stream>>>(x, csr_row, offsets, dinv, z, n);
    stats_kernel<<<512, 128, 0, stream>>>(z, colsum, colsumsq, n);
    finalize_kernel<<<1, 128, 0, stream>>>(colsum, colsumsq, gamma + l * 128,
                                           beta + l * 128, scale, shift, 1.0f / (float)n);
  }
  // last layer: apply BN affine explicitly into d_out (in place)
  norm_kernel<<<2048, 256, 0, stream>>>(z, scale, shift, (float*)d_out, (n * 128) / 4);
}

// Round 2
// 921.327 us; speedup vs baseline: 1.7738x; 1.7738x over previous
//
#include <hip/hip_runtime.h>
#include <cstdint>
#include <cstddef>

#define BN_EPS 1e-5f

// ---------------- graph preprocessing ----------------

__device__ __forceinline__ int edge_at(const void* e, long long i, int m64) {
  return m64 ? (int)((const long long*)e)[i] : ((const int*)e)[i];
}

// Detect int64 vs int32 edge_index: values are 0..99999 (non-negative, <2^31),
// so for int64 data every odd 32-bit word is 0.
__global__ void detect_kernel(const int* __restrict__ e, int* __restrict__ mode) {
  int nz = 0;
  for (int i = 1; i < 512; i += 2) nz |= e[i];
  mode[0] = (nz == 0) ? 1 : 0;
}

__global__ void deg_kernel(const void* __restrict__ edges, const int* __restrict__ mode,
                           int* __restrict__ deg, int E) {
  int m = mode[0];
  long long i = (long long)blockIdx.x * blockDim.x + threadIdx.x;
  long long stride = (long long)gridDim.x * blockDim.x;
  for (; i < E; i += stride) {
    atomicAdd(&deg[edge_at(edges, (long long)E + i, m)], 1);
  }
}

__global__ void dinv_kernel(const int* __restrict__ deg, float* __restrict__ dinv, int n) {
  int i = blockIdx.x * blockDim.x + threadIdx.x;
  if (i < n) dinv[i] = deg[i] > 0 ? rsqrtf((float)deg[i]) : 0.f;
}

// ---- hierarchical exclusive scan of deg -> offsets (+cursor) ----
// k1: thread owns 4 contiguous elems; LDS scan over 256 threads; store
//     per-thread exclusive prefix (tprefix) and per-block total (bsum).
__global__ __launch_bounds__(256) void scan1_kernel(const int* __restrict__ deg,
                                                    int* __restrict__ tprefix,
                                                    int* __restrict__ bsum, int n) {
  __shared__ int s[256];
  int t = threadIdx.x;
  int gid = blockIdx.x * 256 + t;
  int base = gid * 4;
  int sum = 0;
#pragma unroll
  for (int j = 0; j < 4; j++) {
    int i = base + j;
    if (i < n) sum += deg[i];
  }
  s[t] = sum;
  __syncthreads();
  for (int off = 1; off < 256; off <<= 1) {
    int v = (t >= off) ? s[t - off] : 0;
    __syncthreads();
    s[t] += v;
    __syncthreads();
  }
  tprefix[gid] = s[t] - sum;  // exclusive within block
  if (t == 255) bsum[blockIdx.x] = s[255];
}

// k2: single block scans bsum (nb <= 256) in place to exclusive; writes offsets[n]=total
__global__ __launch_bounds__(256) void scan2_kernel(int* __restrict__ bsum, int nb,
                                                    int* __restrict__ offsets, int n) {
  __shared__ int s[256];
  int t = threadIdx.x;
  int v = (t < nb) ? bsum[t] : 0;
  s[t] = v;
  __syncthreads();
  for (int off = 1; off < 256; off <<= 1) {
    int u = (t >= off) ? s[t - off] : 0;
    __syncthreads();
    s[t] += u;
    __syncthreads();
  }
  if (t < nb) bsum[t] = s[t] - v;  // exclusive
  if (t == 255) offsets[n] = s[255];
}

// k3: write offsets + cursor
__global__ __launch_bounds__(256) void scan3_kernel(const int* __restrict__ deg,
                                                    const int* __restrict__ tprefix,
                                                    const int* __restrict__ bsum,
                                                    int* __restrict__ offsets,
                                                    int* __restrict__ cursor, int n) {
  int gid = blockIdx.x * 256 + threadIdx.x;
  int run = bsum[blockIdx.x] + tprefix[gid];
  int base = gid * 4;
#pragma unroll
  for (int j = 0; j < 4; j++) {
    int i = base + j;
    if (i < n) {
      offsets[i] = run;
      cursor[i] = run;
      run += deg[i];
    }
  }
}

__global__ void fill_kernel(const void* __restrict__ edges, const int* __restrict__ mode,
                            int* __restrict__ cursor, int* __restrict__ csr_row, int E) {
  int m = mode[0];
  long long i = (long long)blockIdx.x * blockDim.x + threadIdx.x;
  long long stride = (long long)gridDim.x * blockDim.x;
  for (; i < E; i += stride) {
    int c = edge_at(edges, (long long)E + i, m);
    int r = edge_at(edges, i, m);
    int p = atomicAdd(&cursor[c], 1);
    csr_row[p] = r;
  }
}

// ---------------- per-layer kernels ----------------

// x[i][:] = dinv[i] * ( affine(in[i][:]) @ W )
__global__ __launch_bounds__(256) void gemm_kernel(
    const float* __restrict__ in, const float* __restrict__ W,
    const float* __restrict__ scale, const float* __restrict__ shift, int use_affine,
    const float* __restrict__ dinv, float* __restrict__ x, int n) {
  __shared__ float A[64][33];
  __shared__ float Bs[32][128];
  int tid = threadIdx.x;
  int row0 = blockIdx.x * 64;
  int tc = tid & 15;
  int tr = tid >> 4;
  float acc[4][8] = {};

  for (int kt = 0; kt < 128; kt += 32) {
    {
      int r = tid >> 2;
      int c = (tid & 3) * 8;
      int grow = row0 + r;
      if (grow < n) {
        const float* src = in + (size_t)grow * 128 + kt + c;
        float4 v0 = *(const float4*)(src);
        float4 v1 = *(const float4*)(src + 4);
        float vv[8] = {v0.x, v0.y, v0.z, v0.w, v1.x, v1.y, v1.z, v1.w};
        if (use_affine) {
#pragma unroll
          for (int j = 0; j < 8; j++) vv[j] = vv[j] * scale[kt + c + j] + shift[kt + c + j];
        }
#pragma unroll
        for (int j = 0; j < 8; j++) A[r][c + j] = vv[j];
      } else {
#pragma unroll
        for (int j = 0; j < 8; j++) A[r][c + j] = 0.f;
      }
    }
    {
      int kr = tid >> 3;
      int c = (tid & 7) * 16;
      const float* src = W + (size_t)(kt + kr) * 128 + c;
      float4* dst = (float4*)&Bs[kr][c];
      dst[0] = ((const float4*)src)[0];
      dst[1] = ((const float4*)src)[1];
      dst[2] = ((const float4*)src)[2];
      dst[3] = ((const float4*)src)[3];
    }
    __syncthreads();
#pragma unroll
    for (int k = 0; k < 32; k++) {
      float av[4];
#pragma unroll
      for (int i = 0; i < 4; i++) av[i] = A[tr * 4 + i][k];
      float4 b0 = *(const float4*)&Bs[k][tc * 8];
      float4 b1 = *(const float4*)&Bs[k][tc * 8 + 4];
      float bv[8] = {b0.x, b0.y, b0.z, b0.w, b1.x, b1.y, b1.z, b1.w};
#pragma unroll
      for (int i = 0; i < 4; i++)
#pragma unroll
        for (int j = 0; j < 8; j++) acc[i][j] += av[i] * bv[j];
    }
    __syncthreads();
  }

#pragma unroll
  for (int i = 0; i < 4; i++) {
    int grow = row0 + tr * 4 + i;
    if (grow < n) {
      float dv = dinv[grow];
      float4 o0 = make_float4(acc[i][0] * dv, acc[i][1] * dv, acc[i][2] * dv, acc[i][3] * dv);
      float4 o1 = make_float4(acc[i][4] * dv, acc[i][5] * dv, acc[i][6] * dv, acc[i][7] * dv);
      *(float4*)(x + (size_t)grow * 128 + tc * 8) = o0;
      *(float4*)(x + (size_t)grow * 128 + tc * 8 + 4) = o1;
    }
  }
}

// z[c][:] = dinv[c] * sum over incoming edges of x[row][:]
// 32 lanes per node (float4 each), unroll-by-4 with 4 independent accumulators.
__global__ __launch_bounds__(256) void agg_kernel(
    const float4* __restrict__ x4, const int* __restrict__ csr_row,
    const int* __restrict__ offsets, const float* __restrict__ dinv,
    float4* __restrict__ z4, int n) {
  int node = blockIdx.x * 8 + (threadIdx.x >> 5);
  int d4 = threadIdx.x & 31;
  if (node >= n) return;
  int lo = offsets[node], hi = offsets[node + 1];
  float4 a0 = {0, 0, 0, 0}, a1 = {0, 0, 0, 0}, a2 = {0, 0, 0, 0}, a3 = {0, 0, 0, 0};
  int e = lo;
  for (; e + 4 <= hi; e += 4) {
    int r0 = csr_row[e];
    int r1 = csr_row[e + 1];
    int r2 = csr_row[e + 2];
    int r3 = csr_row[e + 3];
    float4 v0 = x4[(size_t)r0 * 32 + d4];
    float4 v1 = x4[(size_t)r1 * 32 + d4];
    float4 v2 = x4[(size_t)r2 * 32 + d4];
    float4 v3 = x4[(size_t)r3 * 32 + d4];
    a0.x += v0.x; a0.y += v0.y; a0.z += v0.z; a0.w += v0.w;
    a1.x += v1.x; a1.y += v1.y; a1.z += v1.z; a1.w += v1.w;
    a2.x += v2.x; a2.y += v2.y; a2.z += v2.z; a2.w += v2.w;
    a3.x += v3.x; a3.y += v3.y; a3.z += v3.z; a3.w += v3.w;
  }
  for (; e < hi; e++) {
    int r = csr_row[e];
    float4 v = x4[(size_t)r * 32 + d4];
    a0.x += v.x; a0.y += v.y; a0.z += v.z; a0.w += v.w;
  }
  float dv = dinv[node];
  float4 s;
  s.x = (a0.x + a1.x + a2.x + a3.x) * dv;
  s.y = (a0.y + a1.y + a2.y + a3.y) * dv;
  s.z = (a0.z + a1.z + a2.z + a3.z) * dv;
  s.w = (a0.w + a1.w + a2.w + a3.w) * dv;
  z4[(size_t)node * 32 + d4] = s;
}

__global__ __launch_bounds__(128) void stats_kernel(
    const float* __restrict__ z, float* __restrict__ colsum,
    float* __restrict__ colsumsq, int n) {
  int d = threadIdx.x;
  float s = 0.f, s2 = 0.f;
  for (int r = blockIdx.x; r < n; r += gridDim.x) {
    float v = z[(size_t)r * 128 + d];
    s += v;
    s2 += v * v;
  }
  atomicAdd(&colsum[d], s);
  atomicAdd(&colsumsq[d], s2);
}

__global__ void finalize_kernel(const float* __restrict__ colsum,
                                const float* __restrict__ colsumsq,
                                const float* __restrict__ gamma,
                                const float* __restrict__ beta,
                                float* __restrict__ scale, float* __restrict__ shift,
                                float invN) {
  int d = threadIdx.x;
  float mu = colsum[d] * invN;
  float var = colsumsq[d] * invN - mu * mu;
  var = fmaxf(var, 0.f);
  float sc = gamma[d] * rsqrtf(var + BN_EPS);
  scale[d] = sc;
  shift[d] = beta[d] - mu * sc;
}

__global__ __launch_bounds__(256) void norm_kernel(
    const float* __restrict__ z, const float* __restrict__ scale,
    const float* __restrict__ shift, float* __restrict__ out, int total4) {
  int idx = blockIdx.x * blockDim.x + threadIdx.x;
  int stride = gridDim.x * blockDim.x;
  for (int i = idx; i < total4; i += stride) {
    float4 v = ((const float4*)z)[i];
    int d0 = (i & 31) * 4;
    v.x = v.x * scale[d0] + shift[d0];
    v.y = v.y * scale[d0 + 1] + shift[d0 + 1];
    v.z = v.z * scale[d0 + 2] + shift[d0 + 2];
    v.w = v.w * scale[d0 + 3] + shift[d0 + 3];
    ((float4*)out)[i] = v;
  }
}

// ---------------- launcher ----------------

extern "C" void kernel_launch(void* const* d_in, const int* in_sizes, int n_in,
                              void* d_out, int out_size, void* d_ws, size_t ws_size,
                              hipStream_t stream) {
  const float* feats = (const float*)d_in[0];
  const void* edges = d_in[1];
  const float* W = (const float*)d_in[2];
  const float* gamma = (const float*)d_in[4];
  const float* beta = (const float*)d_in[5];

  const int n = in_sizes[0] / 128;
  const int E = in_sizes[1] / 2;

  const int scan_blocks = (n + 1023) / 1024;  // 4 elems/thread, 256 threads

  char* ws = (char*)d_ws;
  size_t off = 0;
  float* x = (float*)(ws + off); off += (size_t)n * 128 * 4;
  int* deg = (int*)(ws + off); off += (size_t)n * 4;
  float* dinv = (float*)(ws + off); off += (size_t)n * 4;
  int* offsets = (int*)(ws + off); off += (size_t)(n + 1) * 4; off = (off + 255) & ~(size_t)255;
  int* cursor = (int*)(ws + off); off += (size_t)n * 4; off = (off + 255) & ~(size_t)255;
  int* csr_row = (int*)(ws + off); off += (size_t)E * 4; off = (off + 255) & ~(size_t)255;
  int* tprefix = (int*)(ws + off); off += (size_t)scan_blocks * 256 * 4; off = (off + 255) & ~(size_t)255;
  int* bsum = (int*)(ws + off); off += 256 * 4;
  float* colsum = (float*)(ws + off); off += 128 * 4;
  float* colsumsq = (float*)(ws + off); off += 128 * 4;
  float* scale = (float*)(ws + off); off += 128 * 4;
  float* shift = (float*)(ws + off); off += 128 * 4;
  int* mode = (int*)(ws + off); off += 4;

  // preprocessing (graph is layer-invariant)
  hipMemsetAsync(deg, 0, (size_t)n * 4, stream);
  detect_kernel<<<1, 1, 0, stream>>>((const int*)edges, mode);
  deg_kernel<<<2048, 256, 0, stream>>>(edges, mode, deg, E);
  dinv_kernel<<<(n + 255) / 256, 256, 0, stream>>>(deg, dinv, n);
  scan1_kernel<<<scan_blocks, 256, 0, stream>>>(deg, tprefix, bsum, n);
  scan2_kernel<<<1, 256, 0, stream>>>(bsum, scan_blocks, offsets, n);
  scan3_kernel<<<scan_blocks, 256, 0, stream>>>(deg, tprefix, bsum, offsets, cursor, n);
  fill_kernel<<<2048, 256, 0, stream>>>(edges, mode, cursor, csr_row, E);

  float* z = (float*)d_out;
  for (int l = 0; l < 3; l++) {
    const float* in = (l == 0) ? feats : z;
    gemm_kernel<<<(n + 63) / 64, 256, 0, stream>>>(
        in, W + (size_t)l * 128 * 128, scale, shift, l > 0 ? 1 : 0, dinv, x, n);
    hipMemsetAsync(colsum, 0, 2 * 128 * 4, stream);
    agg_kernel<<<(n + 7) / 8, 256, 0, stream>>>(
        (const float4*)x, csr_row, offsets, dinv, (float4*)z, n);
    stats_kernel<<<512, 128, 0, stream>>>(z, colsum, colsumsq, n);
    finalize_kernel<<<1, 128, 0, stream>>>(colsum, colsumsq, gamma + l * 128,
                                           beta + l * 128, scale, shift, 1.0f / (float)n);
  }
  norm_kernel<<<2048, 256, 0, stream>>>(z, scale, shift, (float*)d_out, (n * 128) / 4);
}